// Round 2
// baseline (310.359 us; speedup 1.0000x reference)
//
#include <hip/hip_runtime.h>

// FixedComplexCell: complex gating with normalized gate.
//   mag  = sqrt(g0^2 + g1^2 + 1e-8)
//   gre  = g0/mag, gim = g1/mag
//   out_re = z_re*gre - z_im*gim
//   out_im = z_re*gim + z_im*gre
// Shapes: z_re, z_im = (B, D) f32; gate = (B, 2, D) f32. B = D = 4096.
// d_out = [out_re (B*D) | out_im (B*D)] f32.
//
// Memory-bound: 24 B/element, roofline ~64 us at 6.3 TB/s.

#define D_DIM 4096
#define D4    (D_DIM / 4)      // 1024 float4 per row
#define G4ROW (2 * D4)         // 2048 float4 per gate row

__global__ __launch_bounds__(256) void FixedComplexCell_18167711662682_kernel(
    const float4* __restrict__ z_re,
    const float4* __restrict__ z_im,
    const float4* __restrict__ gate,
    float4* __restrict__ out_re,
    float4* __restrict__ out_im,
    int n4)
{
    int i = blockIdx.x * blockDim.x + threadIdx.x;
    if (i >= n4) return;

    int b  = i >> 10;          // i / D4
    int d4 = i & (D4 - 1);     // i % D4

    float4 zr = z_re[i];
    float4 zi = z_im[i];
    float4 g0 = gate[b * G4ROW + d4];
    float4 g1 = gate[b * G4ROW + D4 + d4];

    float4 ore, oim;
#define COMP(c)                                          \
    {                                                    \
        float m2  = g0.c * g0.c + g1.c * g1.c + 1e-8f;   \
        float rm  = 1.0f / sqrtf(m2);                    \
        float gre = g0.c * rm;                           \
        float gim = g1.c * rm;                           \
        ore.c = zr.c * gre - zi.c * gim;                 \
        oim.c = zr.c * gim + zi.c * gre;                 \
    }
    COMP(x) COMP(y) COMP(z) COMP(w)
#undef COMP

    out_re[i] = ore;
    out_im[i] = oim;
}

extern "C" void kernel_launch(void* const* d_in, const int* in_sizes, int n_in,
                              void* d_out, int out_size, void* d_ws, size_t ws_size,
                              hipStream_t stream) {
    const float4* z_re = (const float4*)d_in[0];
    const float4* z_im = (const float4*)d_in[1];
    const float4* gate = (const float4*)d_in[2];

    int n  = in_sizes[0];          // B*D elements
    int n4 = n / 4;                // float4 count

    float4* out_re = (float4*)d_out;
    float4* out_im = (float4*)d_out + (size_t)n4;

    int block = 256;
    int grid  = (n4 + block - 1) / block;
    FixedComplexCell_18167711662682_kernel<<<grid, block, 0, stream>>>(
        z_re, z_im, gate, out_re, out_im, n4);
}